// Round 2
// baseline (297.221 us; speedup 1.0000x reference)
//
#include <hip/hip_runtime.h>
#include <hip/hip_bf16.h>

// B=4, S=2048, D=1024; fp32 in/out, bf16 MFMA compute.
// GEMM engine: 256x256 tile, BK=64, 8 waves (512 thr), 8-phase counted-vmcnt
// schedule (T2 swizzle + T3/T4 + T5 setprio), 128 KiB LDS double-buffer.
#define SS 2048
#define DD 1024
#define NB 4

typedef __attribute__((ext_vector_type(8))) short  bf8;    // 8 x bf16
typedef __attribute__((ext_vector_type(4))) float  f32x4;

static __device__ __forceinline__ unsigned short f2bf(float f) {
    unsigned u = __float_as_uint(f);
    u += 0x7fffu + ((u >> 16) & 1u);
    return (unsigned short)(u >> 16);
}

static __device__ __forceinline__ void gload_lds16(const void* g, void* lds) {
    __builtin_amdgcn_global_load_lds((__attribute__((address_space(1))) void*)g,
                                     (__attribute__((address_space(3))) void*)lds,
                                     16, 0, 0);
}

#define SB0()   __builtin_amdgcn_sched_barrier(0)
#define BAR()   __builtin_amdgcn_s_barrier()
#define LGKM0() asm volatile("s_waitcnt lgkmcnt(0)" ::: "memory")
#define VMW(N)  asm volatile("s_waitcnt vmcnt(" #N ")" ::: "memory")

#define QUAD(FM0, FN0, AF, BF) \
  { _Pragma("unroll") for (int ks = 0; ks < 2; ++ks) { \
      _Pragma("unroll") for (int i2 = 0; i2 < 4; ++i2) { \
        _Pragma("unroll") for (int j2 = 0; j2 < 2; ++j2) { \
          acc[FM0 + i2][FN0 + j2] = __builtin_amdgcn_mfma_f32_16x16x32_bf16( \
              AF[i2][ks], BF[j2][ks], acc[FM0 + i2][FN0 + j2], 0, 0, 0); } } } }

#define LDA4(buf, fmb, d) \
  { _Pragma("unroll") for (int i2 = 0; i2 < 4; ++i2) { \
      d[i2][0] = rdA(buf, (fmb) + i2, 0); d[i2][1] = rdA(buf, (fmb) + i2, 1); } }
#define LDB2(buf, fnb, d) \
  { _Pragma("unroll") for (int j2 = 0; j2 < 2; ++j2) { \
      d[j2][0] = rdB(buf, (fnb) + j2, 0); d[j2][1] = rdB(buf, (fnb) + j2, 1); } }

// ---------------- fp32 -> bf16 converts ----------------
__global__ __launch_bounds__(256)
void cvt3(const float* __restrict__ a, const float* __restrict__ b, const float* __restrict__ c,
          unsigned short* __restrict__ oa, unsigned short* __restrict__ ob,
          unsigned short* __restrict__ oc, int n4) {
    int i = blockIdx.x * 256 + threadIdx.x;
    if (i >= n4) return;
    const float* in = blockIdx.y == 0 ? a : blockIdx.y == 1 ? b : c;
    unsigned short* out = blockIdx.y == 0 ? oa : blockIdx.y == 1 ? ob : oc;
    float4 v = ((const float4*)in)[i];
    ushort4 o;
    o.x = f2bf(v.x); o.y = f2bf(v.y); o.z = f2bf(v.z); o.w = f2bf(v.w);
    ((ushort4*)out)[i] = o;
}

// ---------------- 256^2 8-phase bt-GEMM ----------------
// MODE 0: merged QKV projections (z selects; z==2 stores transposed [b][d][s])
// MODE 2: scores  = Q.K^T/32, fp32, causal tile skip
// MODE 3: PV, fp32 out, causal K-limit, split-K (atomicAdd) for large q-tiles
template<int MODE>
__global__ __launch_bounds__(512, 2)
void gemm256(const unsigned short* __restrict__ A0, const unsigned short* __restrict__ B0w,
             const float* __restrict__ bias0, void* __restrict__ C0,
             const unsigned short* __restrict__ A1, const unsigned short* __restrict__ B1w,
             const float* __restrict__ bias1, void* __restrict__ C1,
             const unsigned short* __restrict__ A2, const unsigned short* __restrict__ B2w,
             const float* __restrict__ bias2, void* __restrict__ C2)
{
    constexpr int LDA = (MODE == 3) ? 2048 : 1024;
    constexpr int LDB = (MODE == 3) ? 2048 : 1024;
    const int bx = blockIdx.x, by = blockIdx.y, bz = blockIdx.z;
    if (MODE == 2 && bx > by) return;

    const unsigned short* A;
    const unsigned short* Bm;
    const float* bias = nullptr;
    int len, qy = 0, seg = 0, nsp = 1;
    if (MODE == 0) {
        A    = (bz == 0 ? A0 : bz == 1 ? A1 : A2) + (size_t)by * 256 * LDA;
        Bm   = (bz == 0 ? B0w : bz == 1 ? B1w : B2w) + (size_t)bx * 256 * LDB;
        bias = bz == 0 ? bias0 : bz == 1 ? bias1 : bias2;
        len  = 1024;
    } else if (MODE == 2) {
        A   = A0 + (size_t)bz * SS * DD + (size_t)by * 256 * LDA;
        Bm  = B0w + (size_t)bz * SS * DD + (size_t)bx * 256 * LDB;
        len = 1024;
    } else {
        if (by < 4) { qy = by; seg = 0; nsp = 1; }
        else        { qy = 4 + ((by - 4) >> 1); seg = (by - 4) & 1; nsp = 2; }
        int ktot = (qy + 1) * 256, halfk = ktot >> 1;
        int kst = seg ? halfk : 0;
        len = (nsp == 1) ? ktot : halfk;
        A  = A0  + (size_t)bz * SS * SS + (size_t)qy * 256 * LDA + kst;
        Bm = B0w + (size_t)bz * DD * SS + (size_t)bx * 256 * LDB + kst;
    }

    extern __shared__ __align__(16) char lds[];
    const int tid = threadIdx.x;
    const int l = tid & 63, w = tid >> 6;
    const int wr = w >> 2, wc = w & 3;

    // stage one half-tile (2 x gload16/thread); LDS dest linear, global src
    // pre-swizzled: chunk c = slot ^ (row&7) so swizzled reads see linear data
    auto stg = [&](const unsigned short* src, int ld, char* mb, int half, int tile) {
        #pragma unroll
        for (int j = 0; j < 2; ++j) {
            int rr = half * 128 + (w * 2 + j) * 8 + (l >> 3);
            int cc = (l & 7) ^ (l >> 3);
            gload_lds16(src + (size_t)rr * ld + tile * 64 + cc * 8,
                        mb + half * 16384 + (w * 2 + j) * 1024);
        }
    };
    auto rdA = [&](int buf, int fm, int ks) -> bf8 {
        int row = wr * 128 + fm * 16 + (l & 15);
        return *(const bf8*)(lds + buf * 65536 + row * 128 +
                             ((((ks << 2) + (l >> 4)) ^ (l & 7)) << 4));
    };
    auto rdB = [&](int buf, int fn, int ks) -> bf8 {
        int row = wc * 64 + fn * 16 + (l & 15);
        return *(const bf8*)(lds + buf * 65536 + 32768 + row * 128 +
                             ((((ks << 2) + (l >> 4)) ^ (l & 7)) << 4));
    };

    char* A0b = lds;                 char* B0b = lds + 32768;
    char* A1b = lds + 65536;         char* B1b = lds + 98304;

    f32x4 acc[8][4];
    #pragma unroll
    for (int i2 = 0; i2 < 8; ++i2)
        #pragma unroll
        for (int j2 = 0; j2 < 4; ++j2) acc[i2][j2] = (f32x4){0.f, 0.f, 0.f, 0.f};

    bf8 aA[4][2], aB[4][2], bL[2][2], bH[2][2];

    const int NT = len >> 6;
    // prologue: tile0 full -> buf0, tile1 A-halves -> buf1 (12 issues/wave)
    stg(A, LDA, A0b, 0, 0);  stg(A, LDA, A0b, 1, 0);
    stg(Bm, LDB, B0b, 0, 0); stg(Bm, LDB, B0b, 1, 0);
    stg(A, LDA, A1b, 0, 1);  stg(A, LDA, A1b, 1, 1);
    VMW(4); BAR(); SB0();

    for (int it = 0; it < NT / 2 - 1; ++it) {
        const int t1o = 2 * it + 1, t2 = 2 * it + 2, t3 = 2 * it + 3;
        // p0
        LDA4(0, 0, aA); LDB2(0, 0, bL);
        stg(Bm, LDB, B1b, 0, t1o);
        SB0(); BAR(); LGKM0(); SB0();
        __builtin_amdgcn_s_setprio(1); QUAD(0, 0, aA, bL); __builtin_amdgcn_s_setprio(0);
        SB0(); BAR(); SB0();
        // p1
        LDA4(0, 4, aB);
        stg(Bm, LDB, B1b, 1, t1o);
        SB0(); BAR(); LGKM0(); SB0();
        __builtin_amdgcn_s_setprio(1); QUAD(4, 0, aB, bL); __builtin_amdgcn_s_setprio(0);
        SB0(); BAR(); SB0();
        // p2
        LDB2(0, 2, bH);
        stg(A, LDA, A0b, 0, t2);
        SB0(); BAR(); LGKM0(); SB0();
        __builtin_amdgcn_s_setprio(1); QUAD(4, 2, aB, bH); __builtin_amdgcn_s_setprio(0);
        SB0(); BAR(); SB0();
        // p3 (+vmcnt(4): tile t1o fully landed for p4-p7)
        stg(A, LDA, A0b, 1, t2);
        SB0(); BAR(); SB0();
        __builtin_amdgcn_s_setprio(1); QUAD(0, 2, aA, bH); __builtin_amdgcn_s_setprio(0);
        SB0(); VMW(4); BAR(); SB0();
        // p4
        LDA4(1, 0, aA); LDB2(1, 0, bL);
        stg(Bm, LDB, B0b, 0, t2);
        SB0(); BAR(); LGKM0(); SB0();
        __builtin_amdgcn_s_setprio(1); QUAD(0, 0, aA, bL); __builtin_amdgcn_s_setprio(0);
        SB0(); BAR(); SB0();
        // p5
        LDA4(1, 4, aB);
        stg(Bm, LDB, B0b, 1, t2);
        SB0(); BAR(); LGKM0(); SB0();
        __builtin_amdgcn_s_setprio(1); QUAD(4, 0, aB, bL); __builtin_amdgcn_s_setprio(0);
        SB0(); BAR(); SB0();
        // p6
        LDB2(1, 2, bH);
        stg(A, LDA, A1b, 0, t3);
        SB0(); BAR(); LGKM0(); SB0();
        __builtin_amdgcn_s_setprio(1); QUAD(4, 2, aB, bH); __builtin_amdgcn_s_setprio(0);
        SB0(); BAR(); SB0();
        // p7 (+vmcnt(4): tile t2 fully landed for next-iter p0-p3)
        stg(A, LDA, A1b, 1, t3);
        SB0(); BAR(); SB0();
        __builtin_amdgcn_s_setprio(1); QUAD(0, 2, aA, bH); __builtin_amdgcn_s_setprio(0);
        SB0(); VMW(4); BAR(); SB0();
    }

    // ---- peeled tail: K-tiles NT-2 (buf0) and NT-1 (buf1) ----
    const int tl = NT - 1;
    LDA4(0, 0, aA); LDB2(0, 0, bL);
    stg(Bm, LDB, B1b, 0, tl);
    stg(Bm, LDB, B1b, 1, tl);
    LDA4(0, 4, aB); LDB2(0, 2, bH);
    __builtin_amdgcn_s_setprio(1);
    QUAD(0, 0, aA, bL); QUAD(4, 0, aB, bL); QUAD(4, 2, aB, bH); QUAD(0, 2, aA, bH);
    __builtin_amdgcn_s_setprio(0);
    SB0(); VMW(0); BAR(); SB0();
    LDA4(1, 0, aA); LDB2(1, 0, bL); LDA4(1, 4, aB); LDB2(1, 2, bH);
    __builtin_amdgcn_s_setprio(1);
    QUAD(0, 0, aA, bL); QUAD(4, 0, aB, bL); QUAD(4, 2, aB, bH); QUAD(0, 2, aA, bH);
    __builtin_amdgcn_s_setprio(0);

    // ---- epilogue ----
    const int mb0 = ((MODE == 3) ? qy * 256 : by * 256) + wr * 128;
    const int nb0 = bx * 256 + wc * 64;
    if (MODE == 0) {
        float bv[4];
        #pragma unroll
        for (int fn = 0; fn < 4; ++fn) bv[fn] = bias[nb0 + fn * 16 + (l & 15)];
        if (bz < 2) {
            unsigned short* C = (unsigned short*)(bz == 0 ? C0 : C1);
            #pragma unroll
            for (int fm = 0; fm < 8; ++fm) {
                int m0 = mb0 + fm * 16 + ((l >> 4) << 2);
                #pragma unroll
                for (int fn = 0; fn < 4; ++fn) {
                    int n = nb0 + fn * 16 + (l & 15);
                    #pragma unroll
                    for (int r = 0; r < 4; ++r)
                        C[(size_t)(m0 + r) * DD + n] = f2bf(acc[fm][fn][r] + bv[fn]);
                }
            }
        } else {
            unsigned short* C = (unsigned short*)C2;
            int batch = (by * 256) >> 11;
            int sbase = by * 256 - batch * SS + wr * 128;
            #pragma unroll
            for (int fm = 0; fm < 8; ++fm) {
                int s0 = sbase + fm * 16 + ((l >> 4) << 2);
                #pragma unroll
                for (int fn = 0; fn < 4; ++fn) {
                    int n = nb0 + fn * 16 + (l & 15);
                    ushort4 pk;
                    pk.x = f2bf(acc[fm][fn][0] + bv[fn]);
                    pk.y = f2bf(acc[fm][fn][1] + bv[fn]);
                    pk.z = f2bf(acc[fm][fn][2] + bv[fn]);
                    pk.w = f2bf(acc[fm][fn][3] + bv[fn]);
                    *(ushort4*)&C[(size_t)batch * DD * SS + (size_t)n * SS + s0] = pk;
                }
            }
        }
    } else if (MODE == 2) {
        float* C = (float*)C0 + (size_t)bz * SS * SS;
        #pragma unroll
        for (int fm = 0; fm < 8; ++fm) {
            int m0 = mb0 + fm * 16 + ((l >> 4) << 2);
            #pragma unroll
            for (int fn = 0; fn < 4; ++fn) {
                int n = nb0 + fn * 16 + (l & 15);
                #pragma unroll
                for (int r = 0; r < 4; ++r)
                    C[(size_t)(m0 + r) * SS + n] = acc[fm][fn][r] * 0.03125f;
            }
        }
    } else {
        float* C = (float*)C0 + (size_t)bz * SS * DD;
        #pragma unroll
        for (int fm = 0; fm < 8; ++fm) {
            int m0 = mb0 + fm * 16 + ((l >> 4) << 2);
            #pragma unroll
            for (int fn = 0; fn < 4; ++fn) {
                int n = nb0 + fn * 16 + (l & 15);
                if (nsp == 1) {
                    #pragma unroll
                    for (int r = 0; r < 4; ++r)
                        C[(size_t)(m0 + r) * DD + n] = acc[fm][fn][r];
                } else {
                    #pragma unroll
                    for (int r = 0; r < 4; ++r)
                        atomicAdd(&C[(size_t)(m0 + r) * DD + n], acc[fm][fn][r]);
                }
            }
        }
    }
}

// ---------------- causal row softmax: fp32 scores -> bf16 P ----------------
__global__ __launch_bounds__(256)
void softmax_causal(const float* __restrict__ Sb, unsigned short* __restrict__ P) {
    __shared__ float tmp[8];
    int row = blockIdx.x;
    int b = row >> 11, q = row & 2047;
    const float* s = Sb + ((size_t)b * SS + q) * SS;
    unsigned short* p = P + ((size_t)b * SS + q) * SS;
    int len  = q + 1;
    int wlen = ((q >> 8) + 1) << 8;            // zero-pad to 256 for PV tiles

    float mx = -3e38f;
    for (int i = threadIdx.x; i < len; i += 256) mx = fmaxf(mx, s[i]);
    #pragma unroll
    for (int o = 32; o; o >>= 1) mx = fmaxf(mx, __shfl_xor(mx, o));
    if ((threadIdx.x & 63) == 0) tmp[threadIdx.x >> 6] = mx;
    __syncthreads();
    mx = fmaxf(fmaxf(tmp[0], tmp[1]), fmaxf(tmp[2], tmp[3]));

    float sum = 0.f;
    for (int i = threadIdx.x; i < len; i += 256) sum += __expf(s[i] - mx);
    #pragma unroll
    for (int o = 32; o; o >>= 1) sum += __shfl_xor(sum, o);
    if ((threadIdx.x & 63) == 0) tmp[4 + (threadIdx.x >> 6)] = sum;
    __syncthreads();
    sum = tmp[4] + tmp[5] + tmp[6] + tmp[7];
    float inv = 1.f / sum;

    for (int i = threadIdx.x; i < wlen; i += 256) {
        float e = (i < len) ? __expf(s[i] - mx) * inv : 0.f;
        p[i] = f2bf(e);
    }
}

// ---------------- launch ----------------
extern "C" void kernel_launch(void* const* d_in, const int* in_sizes, int n_in,
                              void* d_out, int out_size, void* d_ws, size_t ws_size,
                              hipStream_t stream) {
    constexpr size_t NX = (size_t)NB * SS * DD;
    constexpr size_t NW = (size_t)DD * DD;

    const float* q   = (const float*)d_in[0];
    const float* k   = (const float*)d_in[1];
    const float* v   = (const float*)d_in[2];
    const float* w_q = (const float*)d_in[4];
    const float* b_q = (const float*)d_in[5];
    const float* w_k = (const float*)d_in[6];
    const float* b_k = (const float*)d_in[7];
    const float* w_v = (const float*)d_in[8];
    const float* b_v = (const float*)d_in[9];
    float* out = (float*)d_out;

    char* ws = (char*)d_ws;
    size_t off = 0;
    auto take = [&](size_t bytes) { char* p = ws + off; off += (bytes + 255) & ~(size_t)255; return p; };
    unsigned short* qb  = (unsigned short*)take(NX * 2);
    unsigned short* kb  = (unsigned short*)take(NX * 2);
    unsigned short* vb  = (unsigned short*)take(NX * 2);
    unsigned short* wqb = (unsigned short*)take(NW * 2);
    unsigned short* wkb = (unsigned short*)take(NW * 2);
    unsigned short* wvb = (unsigned short*)take(NW * 2);
    unsigned short* Qp  = (unsigned short*)take(NX * 2);
    unsigned short* Kp  = (unsigned short*)take(NX * 2);
    unsigned short* VpT = (unsigned short*)take(NX * 2);   // [b][d][s]
    float*          Sb  = (float*)take((size_t)NB * SS * SS * 4);
    unsigned short* P   = qb;   // 33.5 MB: overlays dead qb+kb after projections

    dim3 blk(256);
    cvt3<<<dim3(NX / 4 / 256, 3), blk, 0, stream>>>(q, k, v, qb, kb, vb, (int)(NX / 4));
    cvt3<<<dim3(NW / 4 / 256, 3), blk, 0, stream>>>(w_q, w_k, w_v, wqb, wkb, wvb, (int)(NW / 4));
    hipMemsetAsync(d_out, 0, NB * (size_t)SS * DD * 4, stream);  // PV split-K accumulates

    constexpr size_t LDSB = 131072;
    // merged projections: grid (n-tiles, m-tiles, which-proj)
    gemm256<0><<<dim3(4, 32, 3), dim3(512), LDSB, stream>>>(
        qb, wqb, b_q, Qp,  kb, wkb, b_k, Kp,  vb, wvb, b_v, VpT);
    // scores: causal tile skip
    gemm256<2><<<dim3(8, 8, 4), dim3(512), LDSB, stream>>>(
        Qp, Kp, nullptr, Sb, nullptr, nullptr, nullptr, nullptr,
        nullptr, nullptr, nullptr, nullptr);
    softmax_causal<<<dim3(NB * SS), blk, 0, stream>>>(Sb, P);
    // PV: y encodes (q-tile, K-split segment)
    gemm256<3><<<dim3(4, 12, 4), dim3(512), LDSB, stream>>>(
        P, VpT, nullptr, out, nullptr, nullptr, nullptr, nullptr,
        nullptr, nullptr, nullptr, nullptr);
}